// Round 5
// baseline (267.138 us; speedup 1.0000x reference)
//
#include <hip/hip_runtime.h>
#include <hip/hip_fp16.h>
#include <math.h>

#define N_NODES 100000
#define N_EDGES 1600000
#define D_FEAT  64

#define NSLICE  8      // feature slices: 8 fp16 = 16 B per node per slice
#define SLICE_F 8
#define NCHUNK  3125   // node chunks per slice (32 nodes/block), 3125*32 = 100000

#define NPB     512                                // nodes per bucket (dst>>9)
#define NB      ((N_NODES + NPB - 1) / NPB)        // 196 buckets
#define F1_WGS  512                                // chunking WGs for hist/bucketize
#define CHUNK_E ((N_EDGES + F1_WGS - 1) / F1_WGS)  // 3125 edges per WG
#define STAGE_CAP 16384                            // bucket_csr LDS staging (64 KB)

// ---- helpers ------------------------------------------------------------

__device__ __forceinline__ void unp8(uint4 u, float* a) {
    { __half2 h = *(__half2*)&u.x; float2 f = __half22float2(h); a[0]=f.x; a[1]=f.y; }
    { __half2 h = *(__half2*)&u.y; float2 f = __half22float2(h); a[2]=f.x; a[3]=f.y; }
    { __half2 h = *(__half2*)&u.z; float2 f = __half22float2(h); a[4]=f.x; a[5]=f.y; }
    { __half2 h = *(__half2*)&u.w; float2 f = __half22float2(h); a[6]=f.x; a[7]=f.y; }
}

__device__ __forceinline__ uint4 pack8(const float* v) {
    __half2 h0 = __floats2half2_rn(v[0], v[1]);
    __half2 h1 = __floats2half2_rn(v[2], v[3]);
    __half2 h2 = __floats2half2_rn(v[4], v[5]);
    __half2 h3 = __floats2half2_rn(v[6], v[7]);
    uint4 st;
    st.x = *(unsigned*)&h0; st.y = *(unsigned*)&h1;
    st.z = *(unsigned*)&h2; st.w = *(unsigned*)&h3;
    return st;
}

// ---- CSR build: two-level counting sort, all hot atomics in LDS ---------

__global__ void bucket_hist(const int* __restrict__ dst,
                            int* __restrict__ percnt) {
    __shared__ int cnt[NB];
    for (int i = threadIdx.x; i < NB; i += blockDim.x) cnt[i] = 0;
    __syncthreads();
    int e0 = blockIdx.x * CHUNK_E;
    int e1 = min(e0 + CHUNK_E, N_EDGES);
    for (int e = e0 + threadIdx.x; e < e1; e += blockDim.x)
        atomicAdd(&cnt[dst[e] >> 9], 1);
    __syncthreads();
    for (int i = threadIdx.x; i < NB; i += blockDim.x)
        percnt[i * F1_WGS + blockIdx.x] = cnt[i];
}

__global__ void bucket_colscan(int* __restrict__ percnt,
                               int* __restrict__ bhist) {
    __shared__ int tmp[F1_WGS];
    int b = blockIdx.x;
    int v = percnt[b * F1_WGS + threadIdx.x];
    tmp[threadIdx.x] = v;
    __syncthreads();
    for (int o = 1; o < F1_WGS; o <<= 1) {
        int t = (threadIdx.x >= o) ? tmp[threadIdx.x - o] : 0;
        __syncthreads();
        tmp[threadIdx.x] += t;
        __syncthreads();
    }
    percnt[b * F1_WGS + threadIdx.x] = tmp[threadIdx.x] - v;  // exclusive
    if (threadIdx.x == F1_WGS - 1) bhist[b] = tmp[F1_WGS - 1];
}

__global__ void bucket_scan(const int* __restrict__ bhist,
                            int* __restrict__ bbase) {
    __shared__ int tmp[256];
    int i = threadIdx.x;
    int v = (i < NB) ? bhist[i] : 0;
    tmp[i] = v;
    __syncthreads();
    for (int o = 1; o < 256; o <<= 1) {
        int t = (i >= o) ? tmp[i - o] : 0;
        __syncthreads();
        tmp[i] += t;
        __syncthreads();
    }
    if (i < NB) bbase[i] = tmp[i] - v;
    if (i == 0) bbase[NB] = N_EDGES;
}

__global__ void bucketize(const int* __restrict__ src,
                          const int* __restrict__ dst,
                          const int* __restrict__ bbase,
                          const int* __restrict__ percnt,
                          unsigned int* __restrict__ tmp) {
    __shared__ int base[NB];
    __shared__ int cur[NB];
    int wg = blockIdx.x;
    for (int i = threadIdx.x; i < NB; i += blockDim.x) {
        base[i] = bbase[i] + percnt[i * F1_WGS + wg];
        cur[i] = 0;
    }
    __syncthreads();
    int e0 = wg * CHUNK_E;
    int e1 = min(e0 + CHUNK_E, N_EDGES);
    for (int e = e0 + threadIdx.x; e < e1; e += blockDim.x) {
        int d = dst[e];
        int b = d >> 9;
        int r = atomicAdd(&cur[b], 1);
        tmp[base[b] + r] = ((unsigned)src[e] << 9) | (unsigned)(d & 511);
    }
}

__global__ __launch_bounds__(NPB) void bucket_csr(
        const unsigned int* __restrict__ tmp,
        const int* __restrict__ bbase,
        int* __restrict__ offsets,
        int* __restrict__ csr_src) {
    __shared__ int cnt[NPB];
    __shared__ int off[NPB];
    __shared__ int stage[STAGE_CAP];
    int b = blockIdx.x;
    int ebase = bbase[b];
    int ecnt  = bbase[b + 1] - ebase;
    int node0 = b * NPB;
    int nodes_in = min(NPB, N_NODES - node0);

    cnt[threadIdx.x] = 0;
    __syncthreads();
    for (int i = threadIdx.x; i < ecnt; i += blockDim.x)
        atomicAdd(&cnt[tmp[ebase + i] & 511], 1);
    __syncthreads();

    int v = cnt[threadIdx.x];
    off[threadIdx.x] = v;
    __syncthreads();
    for (int o = 1; o < NPB; o <<= 1) {
        int t = (threadIdx.x >= o) ? off[threadIdx.x - o] : 0;
        __syncthreads();
        off[threadIdx.x] += t;
        __syncthreads();
    }
    int excl = off[threadIdx.x] - v;
    __syncthreads();
    off[threadIdx.x] = excl;
    cnt[threadIdx.x] = 0;  // reuse as cursor
    if (threadIdx.x < nodes_in) offsets[node0 + threadIdx.x] = ebase + excl;
    if (b == NB - 1 && threadIdx.x == 0) offsets[N_NODES] = N_EDGES;
    __syncthreads();

    if (ecnt <= STAGE_CAP) {
        for (int i = threadIdx.x; i < ecnt; i += blockDim.x) {
            unsigned u = tmp[ebase + i];
            int d = (int)(u & 511);
            int r = atomicAdd(&cnt[d], 1);
            stage[off[d] + r] = (int)(u >> 9);
        }
        __syncthreads();
        for (int i = threadIdx.x; i < ecnt; i += blockDim.x)
            csr_src[ebase + i] = stage[i];
    } else {
        for (int i = threadIdx.x; i < ecnt; i += blockDim.x) {
            unsigned u = tmp[ebase + i];
            int d = (int)(u & 511);
            int r = atomicAdd(&cnt[d], 1);
            csr_src[ebase + off[d] + r] = (int)(u >> 9);
        }
    }
}

// ---- cast f32 rows -> sliced fp16 layout tbl[s][node][8] ----------------

__global__ void cast_feat_sliced(const float* __restrict__ in,
                                 __half* __restrict__ out) {
    int i = blockIdx.x * blockDim.x + threadIdx.x;  // over N_NODES*NSLICE
    if (i >= N_NODES * NSLICE) return;
    int node = i >> 3, s = i & 7;
    const float* p = in + (size_t)node * D_FEAT + s * SLICE_F;
    float4 v0 = *(const float4*)p;
    float4 v1 = *(const float4*)(p + 4);
    float v[8] = {v0.x, v0.y, v0.z, v0.w, v1.x, v1.y, v1.z, v1.w};
    *(uint4*)(out + ((size_t)s * N_NODES + node) * SLICE_F) = pack8(v);
}

// ---- sliced mean-aggregation: one block = one slice x 32 nodes ----------
// slice varies slowest in blockIdx -> co-resident blocks share 1-2 slices
// -> per-XCD working set ~1.6-3.2 MB, L2-resident. 8 lanes per node, lane e
// handles edges e, e+8, ...; 16 B slice load per edge; 3-level shfl reduce.

__global__ void gather_sliced(const __half* __restrict__ tbl_in,
                              const int* __restrict__ offsets,
                              const int* __restrict__ csr,
                              __half* __restrict__ tbl_out) {
    int slice = blockIdx.x / NCHUNK;
    int chunk = blockIdx.x % NCHUNK;
    int node  = chunk * 32 + (threadIdx.x >> 3);   // exact: 3125*32 = 100000
    int elane = threadIdx.x & 7;

    int base = offsets[node];
    int deg  = offsets[node + 1] - base;

    const __half* tbl = tbl_in + (size_t)slice * N_NODES * SLICE_F;

    float acc[8] = {0.f,0.f,0.f,0.f,0.f,0.f,0.f,0.f};
    for (int j = elane; j < deg; j += 8) {
        int s = csr[base + j];
        uint4 u = *(const uint4*)(tbl + (size_t)s * SLICE_F);
        float f[8];
        unp8(u, f);
        #pragma unroll
        for (int t = 0; t < 8; t++) acc[t] += f[t];
    }
    #pragma unroll
    for (int m = 1; m < 8; m <<= 1)
        #pragma unroll
        for (int t = 0; t < 8; t++)
            acc[t] += __shfl_xor(acc[t], m);

    if (elane == 0) {
        float inv = (deg > 0) ? 1.0f / (float)deg : 0.0f;
        float r[8];
        #pragma unroll
        for (int t = 0; t < 8; t++) r[t] = acc[t] * inv;
        *(uint4*)(tbl_out + ((size_t)slice * N_NODES + node) * SLICE_F) = pack8(r);
    }
}

// ---- finalize: one lane per node, coalesced slice reads -----------------

__global__ void finalize_sliced(const __half* __restrict__ x1_s,
                                const __half* __restrict__ x2_s,
                                float* __restrict__ out) {
    int node = blockIdx.x * blockDim.x + threadIdx.x;
    if (node >= N_NODES) return;

    float dot = 0.f, nn1 = 0.f, nn2 = 0.f;
    #pragma unroll
    for (int s = 0; s < NSLICE; s++) {
        size_t o = ((size_t)s * N_NODES + node) * SLICE_F;
        uint4 ua = *(const uint4*)(x1_s + o);
        uint4 ub = *(const uint4*)(x2_s + o);
        float a[8], b[8];
        unp8(ua, a); unp8(ub, b);
        #pragma unroll
        for (int t = 0; t < 8; t++) {
            dot += a[t] * b[t];
            nn1 += a[t] * a[t];
            nn2 += b[t] * b[t];
        }
    }
    float w = dot / fmaxf(sqrtf(nn1) * sqrtf(nn2), 1e-8f);
    float omw = 1.0f - w;

    #pragma unroll
    for (int s = 0; s < NSLICE; s++) {
        size_t o = ((size_t)s * N_NODES + node) * SLICE_F;
        uint4 ua = *(const uint4*)(x1_s + o);   // L2-warm reload
        uint4 ub = *(const uint4*)(x2_s + o);
        float a[8], b[8];
        unp8(ua, a); unp8(ub, b);
        float4 r0, r1;
        r0.x = w*b[0] + omw*a[0]; r0.y = w*b[1] + omw*a[1];
        r0.z = w*b[2] + omw*a[2]; r0.w = w*b[3] + omw*a[3];
        r1.x = w*b[4] + omw*a[4]; r1.y = w*b[5] + omw*a[5];
        r1.z = w*b[6] + omw*a[6]; r1.w = w*b[7] + omw*a[7];
        float* po = out + (size_t)node * D_FEAT + s * SLICE_F;
        *(float4*)po = r0;
        *(float4*)(po + 4) = r1;
    }
}

// ---- launch -------------------------------------------------------------

extern "C" void kernel_launch(void* const* d_in, const int* in_sizes, int n_in,
                              void* d_out, int out_size, void* d_ws, size_t ws_size,
                              hipStream_t stream) {
    const float* feat = (const float*)d_in[0];
    const int*   eidx = (const int*)d_in[1];
    const int*   src  = eidx;
    const int*   dst  = eidx + N_EDGES;

    __half*       feat_s  = (__half*)d_ws;                           // 12.8 MB
    __half*       x1_s    = feat_s + (size_t)N_NODES * D_FEAT;       // 12.8 MB
    __half*       x2_s    = x1_s + (size_t)N_NODES * D_FEAT;         // 12.8 MB
    unsigned int* tmp     = (unsigned int*)x2_s;  // aliased: tmp dead before x2 written
    int*          csr_src = (int*)(x2_s + (size_t)N_NODES * D_FEAT); // 6.4 MB
    int*          offsets = csr_src + N_EDGES;                       // 100001
    int*          percnt  = offsets + (N_NODES + 1);                 // NB*F1_WGS
    int*          bhist   = percnt + NB * F1_WGS;                    // NB
    int*          bbase   = bhist + NB;                              // NB+1
    float*        out     = (float*)d_out;

    const int BLK = 256;

    cast_feat_sliced<<<(N_NODES * NSLICE + BLK - 1) / BLK, BLK, 0, stream>>>(feat, feat_s);

    bucket_hist   <<<F1_WGS, 256, 0, stream>>>(dst, percnt);
    bucket_colscan<<<NB, F1_WGS, 0, stream>>>(percnt, bhist);
    bucket_scan   <<<1, 256, 0, stream>>>(bhist, bbase);
    bucketize     <<<F1_WGS, 256, 0, stream>>>(src, dst, bbase, percnt, tmp);
    bucket_csr    <<<NB, NPB, 0, stream>>>(tmp, bbase, offsets, csr_src);

    gather_sliced<<<NSLICE * NCHUNK, BLK, 0, stream>>>(feat_s, offsets, csr_src, x1_s);
    gather_sliced<<<NSLICE * NCHUNK, BLK, 0, stream>>>(x1_s, offsets, csr_src, x2_s);

    finalize_sliced<<<(N_NODES + BLK - 1) / BLK, BLK, 0, stream>>>(x1_s, x2_s, out);
}